// Round 11
// baseline (151.785 us; speedup 1.0000x reference)
//
#include <hip/hip_runtime.h>

#define Bn 128
#define Dd 32
#define Pp 13
#define Ee 16
#define Hh 4
#define HDim 4
#define Ll 416           // Dd*Pp
#define Rr (Bn*Ll)       // 53248 rows

// ---------------------------------------------------------------------------
// Kernel A: fused encoder + QKV. 256 threads / 64 rows per block, 832 blocks.
// phase1 REWORK: per i, read the FULL 64B w1 line for this wave's 16 units
// once (4x float4, all uniform -> s_load) and do 16 FMAs; 16 accumulators.
// Eliminates the K$ quarter-line waste + 4x re-touch that made every
// s_load an L2 miss (~170cyc x 66 per pass).
// ---------------------------------------------------------------------------
__global__ __launch_bounds__(256, 4) void enc_qkv_kernel(
    const float* __restrict__ board, const float* __restrict__ w1,
    const float* __restrict__ b1, const float* __restrict__ w2,
    const float* __restrict__ b2, const float* __restrict__ w_qkv,
    const float* __restrict__ b_qkv,
    float* __restrict__ Q, float* __restrict__ K, float* __restrict__ V)
{
    __shared__ float sf[64 * 65];    // feats, then h (reused), stride 65
    __shared__ float se[64 * 17];    // enc, stride 17

    const int tid  = threadIdx.x;
    const int wu   = __builtin_amdgcn_readfirstlane(tid >> 6);  // uniform wave id
    const int lane = tid & 63;
    const int row0 = blockIdx.x * 64;

    // ---- stage: coalesced board tile -> LDS (stride 65) ----
    {
        const float4* bsrc = (const float4*)(board + (size_t)row0 * 64);
        #pragma unroll
        for (int k = 0; k < 4; ++k) {
            const int idx = tid + 256 * k;        // 0..1023
            const float4 v = bsrc[idx];
            float* dst = &sf[(idx >> 4) * 65 + 4 * (idx & 15)];
            dst[0] = v.x; dst[1] = v.y; dst[2] = v.z; dst[3] = v.w;
        }
    }
    __syncthreads();

    // per-lane row identity
    const int row = row0 + lane;
    const int bb  = row / Ll;
    const int ll  = row - bb * Ll;
    const int dd  = ll / Pp;
    const int pp  = ll - dd * Pp;
    const float fp = (float)pp, fd = (float)dd;

    // transpose feats into registers (stride-65: 2-way = free)
    float f[64];
    #pragma unroll
    for (int i = 0; i < 64; ++i) f[i] = sf[lane * 65 + i];
    __syncthreads();   // sf free for h now

    // ---- phase 1: wave wu -> hidden units wu*16..wu*16+15; lane = row ----
    {
        const int u0 = wu * 16;                  // uniform
        float a[16];
        #pragma unroll
        for (int t4 = 0; t4 < 4; ++t4) {
            const float4 b4 = *(const float4*)(b1 + u0 + 4 * t4);
            a[4*t4+0] = b4.x; a[4*t4+1] = b4.y;
            a[4*t4+2] = b4.z; a[4*t4+3] = b4.w;
        }
        #pragma unroll
        for (int i = 0; i < 64; ++i) {
            const float fi = f[i];
            const float4* wp = (const float4*)(w1 + i * 64 + u0); // full 64B line
            const float4 w0 = wp[0], w1v = wp[1], w2v = wp[2], w3v = wp[3];
            a[0]  = fmaf(fi, w0.x,  a[0]);  a[1]  = fmaf(fi, w0.y,  a[1]);
            a[2]  = fmaf(fi, w0.z,  a[2]);  a[3]  = fmaf(fi, w0.w,  a[3]);
            a[4]  = fmaf(fi, w1v.x, a[4]);  a[5]  = fmaf(fi, w1v.y, a[5]);
            a[6]  = fmaf(fi, w1v.z, a[6]);  a[7]  = fmaf(fi, w1v.w, a[7]);
            a[8]  = fmaf(fi, w2v.x, a[8]);  a[9]  = fmaf(fi, w2v.y, a[9]);
            a[10] = fmaf(fi, w2v.z, a[10]); a[11] = fmaf(fi, w2v.w, a[11]);
            a[12] = fmaf(fi, w3v.x, a[12]); a[13] = fmaf(fi, w3v.y, a[13]);
            a[14] = fmaf(fi, w3v.z, a[14]); a[15] = fmaf(fi, w3v.w, a[15]);
        }
        // piece / depth rows (64, 65)
        #pragma unroll
        for (int t4 = 0; t4 < 4; ++t4) {
            const float4 wpc = *(const float4*)(w1 + 64 * 64 + u0 + 4 * t4);
            const float4 wdp = *(const float4*)(w1 + 65 * 64 + u0 + 4 * t4);
            a[4*t4+0] = fmaf(fp, wpc.x, a[4*t4+0]);
            a[4*t4+1] = fmaf(fp, wpc.y, a[4*t4+1]);
            a[4*t4+2] = fmaf(fp, wpc.z, a[4*t4+2]);
            a[4*t4+3] = fmaf(fp, wpc.w, a[4*t4+3]);
            a[4*t4+0] = fmaf(fd, wdp.x, a[4*t4+0]);
            a[4*t4+1] = fmaf(fd, wdp.y, a[4*t4+1]);
            a[4*t4+2] = fmaf(fd, wdp.z, a[4*t4+2]);
            a[4*t4+3] = fmaf(fd, wdp.w, a[4*t4+3]);
        }
        #pragma unroll
        for (int t = 0; t < 16; ++t)
            sf[lane * 65 + u0 + t] = fmaxf(a[t], 0.f);   // 2-way = free
    }
    __syncthreads();

    // ---- phase 2a: enc dims 4wu..4wu+3 for all 64 rows; lane = row ----
    {
        float4 e4 = *(const float4*)(b2 + 4 * wu);
        #pragma unroll 4
        for (int j = 0; j < 64; ++j) {
            const float hj = sf[lane * 65 + j];   // 2-way = free
            const float4 w4 = *(const float4*)(w2 + j * 16 + 4 * wu); // s_load
            e4.x = fmaf(hj, w4.x, e4.x);
            e4.y = fmaf(hj, w4.y, e4.y);
            e4.z = fmaf(hj, w4.z, e4.z);
            e4.w = fmaf(hj, w4.w, e4.w);
        }
        se[lane * 17 + 4 * wu + 0] = e4.x;
        se[lane * 17 + 4 * wu + 1] = e4.y;
        se[lane * 17 + 4 * wu + 2] = e4.z;
        se[lane * 17 + 4 * wu + 3] = e4.w;
    }
    __syncthreads();

    // ---- phase 2b: lane = row; wave wu -> qkv outputs 12wu..12wu+11 ----
    {
        float x[16];
        #pragma unroll
        for (int e = 0; e < 16; ++e) x[e] = se[lane * 17 + e];

        float res[12];
        #pragma unroll
        for (int jj = 0; jj < 12; ++jj) {
            const int j = 12 * wu + jj;                          // uniform
            const float4* wr = (const float4*)(w_qkv + j * 16);  // s_load
            const float4 x0 = wr[0], x1 = wr[1], x2 = wr[2], x3 = wr[3];
            float a = b_qkv[j];
            a = fmaf(x[0],  x0.x, a); a = fmaf(x[1],  x0.y, a);
            a = fmaf(x[2],  x0.z, a); a = fmaf(x[3],  x0.w, a);
            a = fmaf(x[4],  x1.x, a); a = fmaf(x[5],  x1.y, a);
            a = fmaf(x[6],  x1.z, a); a = fmaf(x[7],  x1.w, a);
            a = fmaf(x[8],  x2.x, a); a = fmaf(x[9],  x2.y, a);
            a = fmaf(x[10], x2.z, a); a = fmaf(x[11], x2.w, a);
            a = fmaf(x[12], x3.x, a); a = fmaf(x[13], x3.y, a);
            a = fmaf(x[14], x3.z, a); a = fmaf(x[15], x3.w, a);
            res[jj] = a;
        }

        const float SC = 0.72134752044f;   // 0.5 * log2(e)
        #pragma unroll
        for (int m3 = 0; m3 < 3; ++m3) {
            const int m = 3 * wu + m3;         // float4 group: tensor*4 + h
            const int tensor = m >> 2;
            const int h = m & 3;
            float4 vv = make_float4(res[4*m3+0], res[4*m3+1],
                                    res[4*m3+2], res[4*m3+3]);
            if (tensor == 0) { vv.x *= SC; vv.y *= SC; vv.z *= SC; vv.w *= SC; }
            float* basep = (tensor == 0) ? Q : (tensor == 1) ? K : V;
            *(float4*)(basep + (((size_t)(bb * Hh + h)) * Ll + ll) * HDim) = vv;
        }
    }
}

// ---------------------------------------------------------------------------
// Kernel B: attention — r5 structure (blockIdx-uniform K/V -> s_load), but
// 2 q-rows per thread so per-batch compute (~416 cyc) fully covers the
// ~200 cyc s_load latency of the next batch. Grid (512,1); 81% lane eff.
// Max-free single-pass softmax (scores tiny; softmax shift-invariant).
// ---------------------------------------------------------------------------
__global__ __launch_bounds__(256, 8) void attn_kernel(
    const float* __restrict__ Q, const float* __restrict__ K,
    const float* __restrict__ V, float* __restrict__ ATT)
{
    const int bh  = blockIdx.x;           // b*Hh + h
    const int tid = threadIdx.x;
    if (tid >= 208) return;
    const int q0i = tid;
    const int q1i = tid + 208;

    const float4* __restrict__ Kb = (const float4*)K + (size_t)bh * Ll;
    const float4* __restrict__ Vb = (const float4*)V + (size_t)bh * Ll;
    const float4* __restrict__ Qb = (const float4*)Q + (size_t)bh * Ll;
    const float4 qa = Qb[q0i];
    const float4 qb = Qb[q1i];

    float sa = 0.f, sb = 0.f;
    float4 oa = make_float4(0.f, 0.f, 0.f, 0.f);
    float4 ob = make_float4(0.f, 0.f, 0.f, 0.f);

    for (int l0 = 0; l0 < Ll; l0 += 8) {   // 416 = 52*8
        float4 kk[8], vv[8];
        #pragma unroll
        for (int j = 0; j < 8; ++j) { kk[j] = Kb[l0 + j]; vv[j] = Vb[l0 + j]; }
        #pragma unroll
        for (int j = 0; j < 8; ++j) {
            float da = qa.x * kk[j].x;
            da = fmaf(qa.y, kk[j].y, da);
            da = fmaf(qa.z, kk[j].z, da);
            da = fmaf(qa.w, kk[j].w, da);
            float db = qb.x * kk[j].x;
            db = fmaf(qb.y, kk[j].y, db);
            db = fmaf(qb.z, kk[j].z, db);
            db = fmaf(qb.w, kk[j].w, db);
            const float ea = __builtin_amdgcn_exp2f(da);
            const float eb = __builtin_amdgcn_exp2f(db);
            sa += ea; sb += eb;
            oa.x = fmaf(ea, vv[j].x, oa.x);
            oa.y = fmaf(ea, vv[j].y, oa.y);
            oa.z = fmaf(ea, vv[j].z, oa.z);
            oa.w = fmaf(ea, vv[j].w, oa.w);
            ob.x = fmaf(eb, vv[j].x, ob.x);
            ob.y = fmaf(eb, vv[j].y, ob.y);
            ob.z = fmaf(eb, vv[j].z, ob.z);
            ob.w = fmaf(eb, vv[j].w, ob.w);
        }
    }

    const int b = bh >> 2;
    const int h = bh & 3;
    {
        const float inv = 1.0f / sa;
        *(float4*)(ATT + ((size_t)(b * Ll + q0i)) * Ee + h * HDim) =
            make_float4(oa.x * inv, oa.y * inv, oa.z * inv, oa.w * inv);
    }
    {
        const float inv = 1.0f / sb;
        *(float4*)(ATT + ((size_t)(b * Ll + q1i)) * Ee + h * HDim) =
            make_float4(ob.x * inv, ob.y * inv, ob.z * inv, ob.w * inv);
    }
}

// ---------------------------------------------------------------------------
// Kernel C: out projection (16x16 GEMV per row; LDS-transposed w_out).
// ---------------------------------------------------------------------------
__global__ __launch_bounds__(256, 8) void outproj_kernel(
    const float* __restrict__ ATT, const float* __restrict__ w_out,
    const float* __restrict__ b_out, float* __restrict__ out)
{
    __shared__ float sx[256];
    __shared__ float sw[256];   // sw[e*16+o] = w_out[o*16+e]

    const int tid = threadIdx.x;
    const size_t gbase = (size_t)blockIdx.x * 256;
    sx[tid] = ATT[gbase + tid];
    sw[tid] = w_out[(tid & 15) * 16 + (tid >> 4)];
    __syncthreads();

    const int rloc = tid >> 4;
    const int o = tid & 15;
    float acc = b_out[o];
    #pragma unroll
    for (int e = 0; e < 16; ++e)
        acc = fmaf(sx[rloc * 16 + e], sw[e * 16 + o], acc);
    out[gbase + tid] = acc;
}

// ---------------------------------------------------------------------------
extern "C" void kernel_launch(void* const* d_in, const int* in_sizes, int n_in,
                              void* d_out, int out_size, void* d_ws, size_t ws_size,
                              hipStream_t stream) {
    const float* board = (const float*)d_in[0];
    const float* w1    = (const float*)d_in[1];
    const float* b1    = (const float*)d_in[2];
    const float* w2    = (const float*)d_in[3];
    const float* b2    = (const float*)d_in[4];
    const float* w_qkv = (const float*)d_in[5];
    const float* b_qkv = (const float*)d_in[6];
    const float* w_out = (const float*)d_in[7];
    const float* b_out = (const float*)d_in[8];
    float* out = (float*)d_out;

    float* ws  = (float*)d_ws;
    float* Q   = ws;                        // (B,H,L,HD)
    float* K   = ws + (size_t)Rr * Ee;
    float* V   = ws + (size_t)2 * Rr * Ee;
    float* ATT = ws + (size_t)3 * Rr * Ee;  // (B,L,E)

    hipLaunchKernelGGL(enc_qkv_kernel, dim3(Rr / 64), dim3(256), 0, stream,
                       board, w1, b1, w2, b2, w_qkv, b_qkv, Q, K, V);
    hipLaunchKernelGGL(attn_kernel, dim3(Bn * Hh, 1), dim3(256), 0, stream,
                       Q, K, V, ATT);
    hipLaunchKernelGGL(outproj_kernel, dim3((Rr * Ee) / 256), dim3(256), 0, stream,
                       ATT, w_out, b_out, out);
}